// Round 2
// baseline (32933.344 us; speedup 1.0000x reference)
//
#include <hip/hip_runtime.h>
#include <hip/hip_bf16.h>

typedef __attribute__((ext_vector_type(4))) float  fvec4;
typedef __attribute__((ext_vector_type(8))) short  svec8;    // 8 bf16 (4 VGPRs), MFMA A/B frag
typedef __attribute__((ext_vector_type(8))) unsigned short usvec8;
typedef __attribute__((ext_vector_type(4))) unsigned short usvec4;

#define MFMA16 __builtin_amdgcn_mfma_f32_16x16x32_bf16

static __device__ __forceinline__ unsigned short f2bf(float f) {
    __hip_bfloat16 h = __float2bfloat16(f);
    return __builtin_bit_cast(unsigned short, h);
}
static __device__ __forceinline__ float bf2f(unsigned short u) {
    unsigned int v = ((unsigned int)u) << 16;
    return __builtin_bit_cast(float, v);
}

// ---------------- fp32 -> bf16 convert ----------------
__global__ void cvt_kernel(const float* __restrict__ in, unsigned short* __restrict__ out, int n4) {
    int stride = gridDim.x * blockDim.x;
    for (int i = blockIdx.x * blockDim.x + threadIdx.x; i < n4; i += stride) {
        fvec4 v = ((const fvec4*)in)[i];
        usvec4 u;
        u[0] = f2bf(v[0]); u[1] = f2bf(v[1]); u[2] = f2bf(v[2]); u[3] = f2bf(v[3]);
        ((usvec4*)out)[i] = u;
    }
}

// ---------------- GEMM: out[m][n] = sum_k lhs[m][k] * rhs[n][k], K=N=512 ----------------
// (unchanged from round 1 — 0.2% of runtime, verified correct)
template<bool LHS_F32_PERM, bool OUT_PERM>
__global__ __launch_bounds__(256)
void gemm512(const void* __restrict__ lhsv, const unsigned short* __restrict__ rhs,
             void* __restrict__ outv)
{
    __shared__ __align__(16) unsigned short smA[64 * 72];
    __shared__ __align__(16) unsigned short smB[64 * 72];
    const int tid = threadIdx.x;
    const int m0 = blockIdx.x * 64;
    const int n0 = blockIdx.y * 64;
    const int w = tid >> 6, l = tid & 63;
    const int g = l >> 4, r16 = l & 15;
    const int wm = (w >> 1) * 32, wn = (w & 1) * 32;
    const int ri = tid >> 2;            // staging row 0..63
    const int kseg = (tid & 3) * 16;    // staging k segment

    fvec4 acc[2][2] = {};

    for (int k0 = 0; k0 < 512; k0 += 64) {
        if (LHS_F32_PERM) {
            const float* x = (const float*)lhsv;
            int m = m0 + ri;
            size_t base = ((size_t)(m & 15) * 4096 + (size_t)(m >> 4)) * 512 + k0 + kseg;
            usvec8 o0, o1;
            fvec4 v0 = *(const fvec4*)(x + base + 0);
            fvec4 v1 = *(const fvec4*)(x + base + 4);
            fvec4 v2 = *(const fvec4*)(x + base + 8);
            fvec4 v3 = *(const fvec4*)(x + base + 12);
            o0[0]=f2bf(v0[0]); o0[1]=f2bf(v0[1]); o0[2]=f2bf(v0[2]); o0[3]=f2bf(v0[3]);
            o0[4]=f2bf(v1[0]); o0[5]=f2bf(v1[1]); o0[6]=f2bf(v1[2]); o0[7]=f2bf(v1[3]);
            o1[0]=f2bf(v2[0]); o1[1]=f2bf(v2[1]); o1[2]=f2bf(v2[2]); o1[3]=f2bf(v2[3]);
            o1[4]=f2bf(v3[0]); o1[5]=f2bf(v3[1]); o1[6]=f2bf(v3[2]); o1[7]=f2bf(v3[3]);
            *(usvec8*)(smA + ri * 72 + kseg)     = o0;
            *(usvec8*)(smA + ri * 72 + kseg + 8) = o1;
        } else {
            const unsigned short* s = (const unsigned short*)lhsv;
            size_t base = (size_t)(m0 + ri) * 512 + k0 + kseg;
            *(usvec8*)(smA + ri * 72 + kseg)     = *(const usvec8*)(s + base);
            *(usvec8*)(smA + ri * 72 + kseg + 8) = *(const usvec8*)(s + base + 8);
        }
        {
            size_t base = (size_t)(n0 + ri) * 512 + k0 + kseg;
            *(usvec8*)(smB + ri * 72 + kseg)     = *(const usvec8*)(rhs + base);
            *(usvec8*)(smB + ri * 72 + kseg + 8) = *(const usvec8*)(rhs + base + 8);
        }
        __syncthreads();
        #pragma unroll
        for (int kt = 0; kt < 2; ++kt) {
            svec8 a0 = *(const svec8*)(smA + (wm +      r16) * 72 + 32 * kt + 8 * g);
            svec8 a1 = *(const svec8*)(smA + (wm + 16 + r16) * 72 + 32 * kt + 8 * g);
            svec8 b0 = *(const svec8*)(smB + (wn +      r16) * 72 + 32 * kt + 8 * g);
            svec8 b1 = *(const svec8*)(smB + (wn + 16 + r16) * 72 + 32 * kt + 8 * g);
            acc[0][0] = MFMA16(a0, b0, acc[0][0], 0, 0, 0);
            acc[0][1] = MFMA16(a0, b1, acc[0][1], 0, 0, 0);
            acc[1][0] = MFMA16(a1, b0, acc[1][0], 0, 0, 0);
            acc[1][1] = MFMA16(a1, b1, acc[1][1], 0, 0, 0);
        }
        __syncthreads();
    }
    #pragma unroll
    for (int mt = 0; mt < 2; ++mt)
    #pragma unroll
    for (int nt = 0; nt < 2; ++nt)
    #pragma unroll
    for (int r = 0; r < 4; ++r) {
        int m = m0 + wm + 16 * mt + 4 * g + r;
        int n = n0 + wn + 16 * nt + r16;
        float v = acc[mt][nt][r];
        if (OUT_PERM) {
            float* out = (float*)outv;
            out[((size_t)(m & 15) * 4096 + (size_t)(m >> 4)) * 512 + n] = v;
        } else {
            unsigned short* out = (unsigned short*)outv;
            out[(size_t)m * 512 + n] = f2bf(v);
        }
    }
}

// ---------------- recurrence: ONE workgroup, 16 waves, A fully in VGPRs ----------------
// Wave w: ng = w&7 owns n_out in [64*ng, 64*ng+64); kg = w>>3 owns k-half [256*kg, +256).
// Operand-swapped MFMA: D[m=n_out_local][n=batch] = sum_k A[m][k] * state_prev[b=n][k].
//   A-frag:  lane l -> m = l&15,        k = 8*(l>>4)+e   (per 32-k window)
//   B-frag:  lane l -> n = l&15 (=b),   k = 8*(l>>4)+e
//   C/D:     lane l -> n = l&15 (=b),   m = 4*(l>>4)+reg  -> 4 consecutive n_out per lane
// kg1 waves: init acc with bx[t], compute high-K partial, pack bf16 -> lane-linear LDS scratch.
// kg0 waves: compute low-K partial, add kg1's partial, relu, write state LDS (dbuf) + global.
#define RT 4096
__global__ __launch_bounds__(1024)
void recur1cu_kernel(const unsigned short* __restrict__ Abf,   // [512][512] bf16, A[n][k]
                     const unsigned short* __restrict__ bx,    // [65536][512] bf16, row = t*16+b
                     unsigned short* __restrict__ states)      // [65536][512] bf16, row = t*16+b
{
    __shared__ __align__(16) unsigned short st[2][16 * 512];   // state dbuf, row=b (1024B), XOR-swizzled
    __shared__ __align__(16) unsigned short ps[8][2][512];     // partials: [ng][chunk][lane*8], lane-linear
    const int tid = threadIdx.x;
    const int w = tid >> 6, l = tid & 63;
    const int g = l >> 4, r16 = l & 15;
    const int ng = w & 7, kg = w >> 3;
    const int nbase = ng * 64;
    const int kbyte = kg * 512;              // byte offset of this wave's k-half within a state row
    const int swz = (r16 & 7) << 4;          // row-XOR swizzle (16B granular)

    // ---- preload A fragments: af[kt][mt], 128 VGPRs ----
    svec8 af[8][4];
    #pragma unroll
    for (int kt = 0; kt < 8; ++kt)
        #pragma unroll
        for (int mt = 0; mt < 4; ++mt)
            af[kt][mt] = *(const svec8*)(Abf + (size_t)(nbase + 16 * mt + r16) * 512
                                         + kg * 256 + 32 * kt + 8 * g);

    // ---- bx prefetch regs (kg1 waves own bx) ----
    unsigned long long pn[4] = {0, 0, 0, 0};
    if (kg) {
        #pragma unroll
        for (int mt = 0; mt < 4; ++mt)
            pn[mt] = *(const unsigned long long*)(bx + (size_t)r16 * 512 + nbase + 16 * mt + 4 * g);
    }

    for (int t = 0; t < RT; ++t) {
        fvec4 acc[4];
        if (kg) {
            // init acc = bx[t] (consumed prefetch), issue prefetch for t+1
            #pragma unroll
            for (int mt = 0; mt < 4; ++mt) {
                unsigned long long u = pn[mt];
                fvec4 a;
                a[0] = bf2f((unsigned short)(u       & 0xffffu));
                a[1] = bf2f((unsigned short)((u>>16) & 0xffffu));
                a[2] = bf2f((unsigned short)((u>>32) & 0xffffu));
                a[3] = bf2f((unsigned short)((u>>48) & 0xffffu));
                acc[mt] = a;
            }
            if (t + 1 < RT) {
                #pragma unroll
                for (int mt = 0; mt < 4; ++mt)
                    pn[mt] = *(const unsigned long long*)(bx + ((size_t)(t + 1) * 16 + r16) * 512
                                                          + nbase + 16 * mt + 4 * g);
            }
        } else {
            #pragma unroll
            for (int mt = 0; mt < 4; ++mt) acc[mt] = fvec4{0.f, 0.f, 0.f, 0.f};
        }

        if (t > 0) {
            const char* stp = (const char*)&st[(t - 1) & 1][0] + r16 * 1024;
            #pragma unroll
            for (int kt = 0; kt < 8; ++kt) {
                svec8 sb = *(const svec8*)(stp + ((kbyte + 64 * kt + 16 * g) ^ swz));
                acc[0] = MFMA16(af[kt][0], sb, acc[0], 0, 0, 0);
                acc[1] = MFMA16(af[kt][1], sb, acc[1], 0, 0, 0);
                acc[2] = MFMA16(af[kt][2], sb, acc[2], 0, 0, 0);
                acc[3] = MFMA16(af[kt][3], sb, acc[3], 0, 0, 0);
            }
        }

        if (kg) {   // producer: pack high-K partial (+bx) to bf16, lane-linear scratch
            usvec8 c0, c1;
            #pragma unroll
            for (int r = 0; r < 4; ++r) {
                c0[r]     = f2bf(acc[0][r]);
                c0[r + 4] = f2bf(acc[1][r]);
                c1[r]     = f2bf(acc[2][r]);
                c1[r + 4] = f2bf(acc[3][r]);
            }
            *(usvec8*)&ps[ng][0][l * 8] = c0;
            *(usvec8*)&ps[ng][1][l * 8] = c1;
        }
        __syncthreads();    // A: partials visible

        if (!kg) {  // finisher: add partial, relu, write state dbuf + export to global
            usvec8 c0 = *(const usvec8*)&ps[ng][0][l * 8];
            usvec8 c1 = *(const usvec8*)&ps[ng][1][l * 8];
            char* stq = (char*)&st[t & 1][0] + r16 * 1024;
            unsigned short* gout = states + ((size_t)t * 16 + r16) * 512;
            #pragma unroll
            for (int mt = 0; mt < 4; ++mt) {
                usvec4 u;
                #pragma unroll
                for (int r = 0; r < 4; ++r) {
                    float p = (mt == 0) ? bf2f(c0[r])     :
                              (mt == 1) ? bf2f(c0[r + 4]) :
                              (mt == 2) ? bf2f(c1[r])     : bf2f(c1[r + 4]);
                    float f = fmaxf(acc[mt][r] + p, 0.0f);
                    u[r] = f2bf(f);
                }
                int ncol = nbase + 16 * mt + 4 * g;
                *(usvec4*)(stq + ((2 * ncol) ^ swz)) = u;   // b64 LDS write, conflict-free
                *(usvec4*)(gout + ncol) = u;                 // 8B global export
            }
        }
        __syncthreads();    // B: state_t complete before next step reads it
    }
}

extern "C" void kernel_launch(void* const* d_in, const int* in_sizes, int n_in,
                              void* d_out, int out_size, void* d_ws, size_t ws_size,
                              hipStream_t stream) {
    const float* x = (const float*)d_in[0];   // [16][4096][512]
    const float* A = (const float*)d_in[1];   // [512][512]
    const float* B = (const float*)d_in[2];   // [512][512]
    const float* C = (const float*)d_in[3];   // [512][512]
    float* out = (float*)d_out;               // [16][4096][512]

    char* ws = (char*)d_ws;
    unsigned short* Abf = (unsigned short*)(ws + 0);                          // 512KB
    unsigned short* Bbf = (unsigned short*)(ws + (size_t)(1 << 19));          // 512KB
    unsigned short* Cbf = (unsigned short*)(ws + (size_t)(2 << 19));          // 512KB
    unsigned short* bx  = (unsigned short*)(ws + (size_t)(4 << 19));          // 64MB: [65536][512] bf16
    unsigned short* states = (unsigned short*)(ws + (size_t)(4 << 19) + ((size_t)1 << 26)); // 64MB

    cvt_kernel<<<64, 256, 0, stream>>>(A, Abf, 512 * 512 / 4);
    cvt_kernel<<<64, 256, 0, stream>>>(B, Bbf, 512 * 512 / 4);
    cvt_kernel<<<64, 256, 0, stream>>>(C, Cbf, 512 * 512 / 4);

    dim3 grid(1024, 8);
    // bx[t*16+b][n] = sum_d x[b][t][d] * B[n][d]
    gemm512<true, false><<<grid, 256, 0, stream>>>((const void*)x, Bbf, (void*)bx);
    // sequential recurrence on one CU, states[t*16+b][n]
    recur1cu_kernel<<<1, 1024, 0, stream>>>(Abf, bx, states);
    // y[b][t][j] = sum_n states[t*16+b][n] * C[j][n]
    gemm512<false, true><<<grid, 256, 0, stream>>>((const void*)states, Cbf, (void*)out);
}

// Round 3
// 13478.322 us; speedup vs baseline: 2.4434x; 2.4434x over previous
//
#include <hip/hip_runtime.h>
#include <hip/hip_bf16.h>

typedef __attribute__((ext_vector_type(4))) float  fvec4;
typedef __attribute__((ext_vector_type(8))) short  svec8;    // 8 bf16 (4 VGPRs), MFMA A/B frag
typedef __attribute__((ext_vector_type(8))) unsigned short usvec8;
typedef __attribute__((ext_vector_type(4))) unsigned short usvec4;

#define MFMA16 __builtin_amdgcn_mfma_f32_16x16x32_bf16

static __device__ __forceinline__ unsigned short f2bf(float f) {
    __hip_bfloat16 h = __float2bfloat16(f);
    return __builtin_bit_cast(unsigned short, h);
}
static __device__ __forceinline__ float bf2f(unsigned short u) {
    unsigned int v = ((unsigned int)u) << 16;
    return __builtin_bit_cast(float, v);
}

// ---------------- fp32 -> bf16 convert ----------------
__global__ void cvt_kernel(const float* __restrict__ in, unsigned short* __restrict__ out, int n4) {
    int stride = gridDim.x * blockDim.x;
    for (int i = blockIdx.x * blockDim.x + threadIdx.x; i < n4; i += stride) {
        fvec4 v = ((const fvec4*)in)[i];
        usvec4 u;
        u[0] = f2bf(v[0]); u[1] = f2bf(v[1]); u[2] = f2bf(v[2]); u[3] = f2bf(v[3]);
        ((usvec4*)out)[i] = u;
    }
}

// ---------------- GEMM: out[m][n] = sum_k lhs[m][k] * rhs[n][k], K=N=512 ----------------
// (unchanged since round 1 — verified, <1% of runtime)
template<bool LHS_F32_PERM, bool OUT_PERM>
__global__ __launch_bounds__(256)
void gemm512(const void* __restrict__ lhsv, const unsigned short* __restrict__ rhs,
             void* __restrict__ outv)
{
    __shared__ __align__(16) unsigned short smA[64 * 72];
    __shared__ __align__(16) unsigned short smB[64 * 72];
    const int tid = threadIdx.x;
    const int m0 = blockIdx.x * 64;
    const int n0 = blockIdx.y * 64;
    const int w = tid >> 6, l = tid & 63;
    const int g = l >> 4, r16 = l & 15;
    const int wm = (w >> 1) * 32, wn = (w & 1) * 32;
    const int ri = tid >> 2;            // staging row 0..63
    const int kseg = (tid & 3) * 16;    // staging k segment

    fvec4 acc[2][2] = {};

    for (int k0 = 0; k0 < 512; k0 += 64) {
        if (LHS_F32_PERM) {
            const float* x = (const float*)lhsv;
            int m = m0 + ri;
            size_t base = ((size_t)(m & 15) * 4096 + (size_t)(m >> 4)) * 512 + k0 + kseg;
            usvec8 o0, o1;
            fvec4 v0 = *(const fvec4*)(x + base + 0);
            fvec4 v1 = *(const fvec4*)(x + base + 4);
            fvec4 v2 = *(const fvec4*)(x + base + 8);
            fvec4 v3 = *(const fvec4*)(x + base + 12);
            o0[0]=f2bf(v0[0]); o0[1]=f2bf(v0[1]); o0[2]=f2bf(v0[2]); o0[3]=f2bf(v0[3]);
            o0[4]=f2bf(v1[0]); o0[5]=f2bf(v1[1]); o0[6]=f2bf(v1[2]); o0[7]=f2bf(v1[3]);
            o1[0]=f2bf(v2[0]); o1[1]=f2bf(v2[1]); o1[2]=f2bf(v2[2]); o1[3]=f2bf(v2[3]);
            o1[4]=f2bf(v3[0]); o1[5]=f2bf(v3[1]); o1[6]=f2bf(v3[2]); o1[7]=f2bf(v3[3]);
            *(usvec8*)(smA + ri * 72 + kseg)     = o0;
            *(usvec8*)(smA + ri * 72 + kseg + 8) = o1;
        } else {
            const unsigned short* s = (const unsigned short*)lhsv;
            size_t base = (size_t)(m0 + ri) * 512 + k0 + kseg;
            *(usvec8*)(smA + ri * 72 + kseg)     = *(const usvec8*)(s + base);
            *(usvec8*)(smA + ri * 72 + kseg + 8) = *(const usvec8*)(s + base + 8);
        }
        {
            size_t base = (size_t)(n0 + ri) * 512 + k0 + kseg;
            *(usvec8*)(smB + ri * 72 + kseg)     = *(const usvec8*)(rhs + base);
            *(usvec8*)(smB + ri * 72 + kseg + 8) = *(const usvec8*)(rhs + base + 8);
        }
        __syncthreads();
        #pragma unroll
        for (int kt = 0; kt < 2; ++kt) {
            svec8 a0 = *(const svec8*)(smA + (wm +      r16) * 72 + 32 * kt + 8 * g);
            svec8 a1 = *(const svec8*)(smA + (wm + 16 + r16) * 72 + 32 * kt + 8 * g);
            svec8 b0 = *(const svec8*)(smB + (wn +      r16) * 72 + 32 * kt + 8 * g);
            svec8 b1 = *(const svec8*)(smB + (wn + 16 + r16) * 72 + 32 * kt + 8 * g);
            acc[0][0] = MFMA16(a0, b0, acc[0][0], 0, 0, 0);
            acc[0][1] = MFMA16(a0, b1, acc[0][1], 0, 0, 0);
            acc[1][0] = MFMA16(a1, b0, acc[1][0], 0, 0, 0);
            acc[1][1] = MFMA16(a1, b1, acc[1][1], 0, 0, 0);
        }
        __syncthreads();
    }
    #pragma unroll
    for (int mt = 0; mt < 2; ++mt)
    #pragma unroll
    for (int nt = 0; nt < 2; ++nt)
    #pragma unroll
    for (int r = 0; r < 4; ++r) {
        int m = m0 + wm + 16 * mt + 4 * g + r;
        int n = n0 + wn + 16 * nt + r16;
        float v = acc[mt][nt][r];
        if (OUT_PERM) {
            float* out = (float*)outv;
            out[((size_t)(m & 15) * 4096 + (size_t)(m >> 4)) * 512 + n] = v;
        } else {
            unsigned short* out = (unsigned short*)outv;
            out[(size_t)m * 512 + n] = f2bf(v);
        }
    }
}

// ---------------- recurrence: ONE workgroup, 4 waves (1/SIMD, 512-VGPR budget) ----------------
// Wave w owns n_out in [128w, 128w+128), FULL k (no partial exchange).
// A-block per wave = 128 frags (kt 0..15 x mt 0..7):
//   kt 0..11  -> registers (af[12][8] = 384 VGPRs)
//   kt 12..15 -> LDS, staged once in fragment-linear order (lane-linear b128 reads)
// Operand-swapped MFMA (verified in round 2, absmax 0.031):
//   A-frag: lane l -> m = l&15 (n_out local), k = 32kt + 8(l>>4) + e
//   B-frag: lane l -> n = l&15 (batch),       k = 32kt + 8(l>>4) + e
//   C/D:    lane l -> n = l&15 (batch),       m = 4(l>>4) + reg
// bx[t] is loaded at step start and added in the epilogue (latency hides under MFMA),
// so no cross-step prefetch registers are held.
#define RT 4096
__global__ __launch_bounds__(256, 1)
void recur1cu_kernel(const unsigned short* __restrict__ Abf,   // [512][512] bf16, A[n][k]
                     const unsigned short* __restrict__ bx,    // [65536][512] bf16, row = t*16+b
                     unsigned short* __restrict__ states)      // [65536][512] bf16, row = t*16+b
{
    __shared__ __align__(16) unsigned short st[16 * 512];            // 16 KB state, row=b (1KB), XOR-swizzled
    __shared__ __align__(16) unsigned short ldsA[4 * 4 * 8 * 512];   // 128 KB: [w][kt-12][mt][frag 1KB]
    const int tid = threadIdx.x;
    const int w = tid >> 6, l = tid & 63;
    const int g = l >> 4, r16 = l & 15;
    const int nbase = w * 128;
    const int swz = (r16 & 7) << 4;          // row-XOR swizzle (16B granular)

    // ---- stage A kt=12..15 into LDS, fragment-linear (lane-linear, conflict-free reads) ----
    #pragma unroll
    for (int kt = 0; kt < 4; ++kt)
        #pragma unroll
        for (int mt = 0; mt < 8; ++mt) {
            usvec8 v = *(const usvec8*)(Abf + (size_t)(nbase + 16 * mt + r16) * 512
                                        + (12 + kt) * 32 + 8 * g);
            *(usvec8*)(ldsA + (((w * 4 + kt) * 8 + mt) << 9) + l * 8) = v;
        }

    // ---- preload A kt=0..11 into registers (384 VGPRs) ----
    svec8 af[12][8];
    #pragma unroll
    for (int kt = 0; kt < 12; ++kt)
        #pragma unroll
        for (int mt = 0; mt < 8; ++mt)
            af[kt][mt] = *(const svec8*)(Abf + (size_t)(nbase + 16 * mt + r16) * 512
                                         + kt * 32 + 8 * g);

    __syncthreads();   // ldsA visible to all waves (w-local anyway, but cheap)

    for (int t = 0; t < RT; ++t) {
        // A) issue bx[t] loads early; consumed in epilogue (latency hidden by MFMA)
        unsigned long long bq[8];
        {
            const unsigned short* bp = bx + ((size_t)t * 16 + r16) * 512 + nbase + 4 * g;
            #pragma unroll
            for (int mt = 0; mt < 8; ++mt)
                bq[mt] = *(const unsigned long long*)(bp + 16 * mt);
        }

        fvec4 acc[8];
        #pragma unroll
        for (int mt = 0; mt < 8; ++mt) acc[mt] = fvec4{0.f, 0.f, 0.f, 0.f};

        // B) MFMA over full k (state from LDS; A from regs for kt<12, LDS for kt>=12)
        if (t > 0) {
            const char* stp = (const char*)st + r16 * 1024;
            #pragma unroll
            for (int kt = 0; kt < 16; ++kt) {
                svec8 sb = *(const svec8*)(stp + ((64 * kt + 16 * g) ^ swz));
                if (kt < 12) {
                    #pragma unroll
                    for (int mt = 0; mt < 8; ++mt)
                        acc[mt] = MFMA16(af[kt][mt], sb, acc[mt], 0, 0, 0);
                } else {
                    #pragma unroll
                    for (int mt = 0; mt < 8; ++mt) {
                        svec8 sa = *(const svec8*)(ldsA + (((w * 4 + (kt - 12)) * 8 + mt) << 9) + l * 8);
                        acc[mt] = MFMA16(sa, sb, acc[mt], 0, 0, 0);
                    }
                }
            }
            __syncthreads();   // C) all reads of st done before overwrite
        }

        // D) epilogue: + bx, relu, pack bf16; write st (swizzled) + global export
        {
            char* stq = (char*)st + r16 * 1024;
            unsigned short* gout = states + ((size_t)t * 16 + r16) * 512;
            #pragma unroll
            for (int mt = 0; mt < 8; ++mt) {
                unsigned long long u = bq[mt];
                usvec4 o;
                #pragma unroll
                for (int r = 0; r < 4; ++r) {
                    float b = bf2f((unsigned short)((u >> (16 * r)) & 0xffffu));
                    o[r] = f2bf(fmaxf(acc[mt][r] + b, 0.0f));
                }
                int ncol = nbase + 16 * mt + 4 * g;
                *(usvec4*)(stq + ((2 * ncol) ^ swz)) = o;   // 8B LDS write, <=2-way banks
                *(usvec4*)(gout + ncol) = o;                 // 8B global export
            }
        }
        __syncthreads();   // E) st complete before next step's reads
    }
}

extern "C" void kernel_launch(void* const* d_in, const int* in_sizes, int n_in,
                              void* d_out, int out_size, void* d_ws, size_t ws_size,
                              hipStream_t stream) {
    const float* x = (const float*)d_in[0];   // [16][4096][512]
    const float* A = (const float*)d_in[1];   // [512][512]
    const float* B = (const float*)d_in[2];   // [512][512]
    const float* C = (const float*)d_in[3];   // [512][512]
    float* out = (float*)d_out;               // [16][4096][512]

    char* ws = (char*)d_ws;
    unsigned short* Abf = (unsigned short*)(ws + 0);                          // 512KB
    unsigned short* Bbf = (unsigned short*)(ws + (size_t)(1 << 19));          // 512KB
    unsigned short* Cbf = (unsigned short*)(ws + (size_t)(2 << 19));          // 512KB
    unsigned short* bx  = (unsigned short*)(ws + (size_t)(4 << 19));          // 64MB: [65536][512] bf16
    unsigned short* states = (unsigned short*)(ws + (size_t)(4 << 19) + ((size_t)1 << 26)); // 64MB

    cvt_kernel<<<64, 256, 0, stream>>>(A, Abf, 512 * 512 / 4);
    cvt_kernel<<<64, 256, 0, stream>>>(B, Bbf, 512 * 512 / 4);
    cvt_kernel<<<64, 256, 0, stream>>>(C, Cbf, 512 * 512 / 4);

    dim3 grid(1024, 8);
    // bx[t*16+b][n] = sum_d x[b][t][d] * B[n][d]
    gemm512<true, false><<<grid, 256, 0, stream>>>((const void*)x, Bbf, (void*)bx);
    // sequential recurrence on one CU, states[t*16+b][n]
    recur1cu_kernel<<<1, 256, 0, stream>>>(Abf, bx, states);
    // y[b][t][j] = sum_n states[t*16+b][n] * C[j][n]
    gemm512<false, true><<<grid, 256, 0, stream>>>((const void*)states, Cbf, (void*)out);
}

// Round 4
// 12181.744 us; speedup vs baseline: 2.7035x; 1.1064x over previous
//
#include <hip/hip_runtime.h>
#include <hip/hip_bf16.h>

typedef __attribute__((ext_vector_type(4))) float  fvec4;
typedef __attribute__((ext_vector_type(8))) short  svec8;    // 8 bf16 (4 VGPRs), MFMA A/B frag
typedef __attribute__((ext_vector_type(8))) unsigned short usvec8;
typedef __attribute__((ext_vector_type(4))) unsigned short usvec4;
typedef __attribute__((ext_vector_type(4))) unsigned int   uivec4;

#define MFMA16 __builtin_amdgcn_mfma_f32_16x16x32_bf16

static __device__ __forceinline__ unsigned short f2bf(float f) {
    __hip_bfloat16 h = __float2bfloat16(f);
    return __builtin_bit_cast(unsigned short, h);
}
static __device__ __forceinline__ float bf2f(unsigned short u) {
    unsigned int v = ((unsigned int)u) << 16;
    return __builtin_bit_cast(float, v);
}

// ---------------- fp32 -> bf16 convert ----------------
__global__ void cvt_kernel(const float* __restrict__ in, unsigned short* __restrict__ out, int n4) {
    int stride = gridDim.x * blockDim.x;
    for (int i = blockIdx.x * blockDim.x + threadIdx.x; i < n4; i += stride) {
        fvec4 v = ((const fvec4*)in)[i];
        usvec4 u;
        u[0] = f2bf(v[0]); u[1] = f2bf(v[1]); u[2] = f2bf(v[2]); u[3] = f2bf(v[3]);
        ((usvec4*)out)[i] = u;
    }
}

// ---------------- GEMM: out[m][n] = sum_k lhs[m][k] * rhs[n][k], K=N=512 ----------------
// (unchanged since round 1 — verified, ~250us total)
template<bool LHS_F32_PERM, bool OUT_PERM>
__global__ __launch_bounds__(256)
void gemm512(const void* __restrict__ lhsv, const unsigned short* __restrict__ rhs,
             void* __restrict__ outv)
{
    __shared__ __align__(16) unsigned short smA[64 * 72];
    __shared__ __align__(16) unsigned short smB[64 * 72];
    const int tid = threadIdx.x;
    const int m0 = blockIdx.x * 64;
    const int n0 = blockIdx.y * 64;
    const int w = tid >> 6, l = tid & 63;
    const int g = l >> 4, r16 = l & 15;
    const int wm = (w >> 1) * 32, wn = (w & 1) * 32;
    const int ri = tid >> 2;
    const int kseg = (tid & 3) * 16;

    fvec4 acc[2][2] = {};

    for (int k0 = 0; k0 < 512; k0 += 64) {
        if (LHS_F32_PERM) {
            const float* x = (const float*)lhsv;
            int m = m0 + ri;
            size_t base = ((size_t)(m & 15) * 4096 + (size_t)(m >> 4)) * 512 + k0 + kseg;
            usvec8 o0, o1;
            fvec4 v0 = *(const fvec4*)(x + base + 0);
            fvec4 v1 = *(const fvec4*)(x + base + 4);
            fvec4 v2 = *(const fvec4*)(x + base + 8);
            fvec4 v3 = *(const fvec4*)(x + base + 12);
            o0[0]=f2bf(v0[0]); o0[1]=f2bf(v0[1]); o0[2]=f2bf(v0[2]); o0[3]=f2bf(v0[3]);
            o0[4]=f2bf(v1[0]); o0[5]=f2bf(v1[1]); o0[6]=f2bf(v1[2]); o0[7]=f2bf(v1[3]);
            o1[0]=f2bf(v2[0]); o1[1]=f2bf(v2[1]); o1[2]=f2bf(v2[2]); o1[3]=f2bf(v2[3]);
            o1[4]=f2bf(v3[0]); o1[5]=f2bf(v3[1]); o1[6]=f2bf(v3[2]); o1[7]=f2bf(v3[3]);
            *(usvec8*)(smA + ri * 72 + kseg)     = o0;
            *(usvec8*)(smA + ri * 72 + kseg + 8) = o1;
        } else {
            const unsigned short* s = (const unsigned short*)lhsv;
            size_t base = (size_t)(m0 + ri) * 512 + k0 + kseg;
            *(usvec8*)(smA + ri * 72 + kseg)     = *(const usvec8*)(s + base);
            *(usvec8*)(smA + ri * 72 + kseg + 8) = *(const usvec8*)(s + base + 8);
        }
        {
            size_t base = (size_t)(n0 + ri) * 512 + k0 + kseg;
            *(usvec8*)(smB + ri * 72 + kseg)     = *(const usvec8*)(rhs + base);
            *(usvec8*)(smB + ri * 72 + kseg + 8) = *(const usvec8*)(rhs + base + 8);
        }
        __syncthreads();
        #pragma unroll
        for (int kt = 0; kt < 2; ++kt) {
            svec8 a0 = *(const svec8*)(smA + (wm +      r16) * 72 + 32 * kt + 8 * g);
            svec8 a1 = *(const svec8*)(smA + (wm + 16 + r16) * 72 + 32 * kt + 8 * g);
            svec8 b0 = *(const svec8*)(smB + (wn +      r16) * 72 + 32 * kt + 8 * g);
            svec8 b1 = *(const svec8*)(smB + (wn + 16 + r16) * 72 + 32 * kt + 8 * g);
            acc[0][0] = MFMA16(a0, b0, acc[0][0], 0, 0, 0);
            acc[0][1] = MFMA16(a0, b1, acc[0][1], 0, 0, 0);
            acc[1][0] = MFMA16(a1, b0, acc[1][0], 0, 0, 0);
            acc[1][1] = MFMA16(a1, b1, acc[1][1], 0, 0, 0);
        }
        __syncthreads();
    }
    #pragma unroll
    for (int mt = 0; mt < 2; ++mt)
    #pragma unroll
    for (int nt = 0; nt < 2; ++nt)
    #pragma unroll
    for (int r = 0; r < 4; ++r) {
        int m = m0 + wm + 16 * mt + 4 * g + r;
        int n = n0 + wn + 16 * nt + r16;
        float v = acc[mt][nt][r];
        if (OUT_PERM) {
            float* out = (float*)outv;
            out[((size_t)(m & 15) * 4096 + (size_t)(m >> 4)) * 512 + n] = v;
        } else {
            unsigned short* out = (unsigned short*)outv;
            out[(size_t)m * 512 + n] = f2bf(v);
        }
    }
}

// ---------------- recurrence: ONE workgroup, 4 waves (1/SIMD, 512-VGPR budget) ----------------
// Wave w owns n_out in [128w, 128w+128), FULL k.
// A-split per wave (128 frags total):
//   mt 0..5  x kt 0..15 -> registers  (96 frags = 384 VGPR)
//   mt 6..7  x kt 0..15 -> LDS        (32 frags = 32KB/wave, 128KB total, frag-linear)
// This gives an even per-kt LDS mix (1 state + 2 A reads per 8 MFMAs) so the LDS pipe
// (~750 cyc/step at 256B/clk) and MFMA pipe (~620 cyc/step) stay balanced.
// Software-pipelined ds_reads (distance 2 for state, 1 for LDS-A) + per-kt
// sched_group_barrier cap transient pressure so af is never a spill victim.
// Mappings (verified rounds 2-3, absmax 0.03125):
//   A-frag: lane l -> m = l&15 (n_out local), k = 32kt + 8(l>>4) + e
//   B-frag: lane l -> n = l&15 (batch),       k = 32kt + 8(l>>4) + e
//   C/D:    lane l -> n = l&15 (batch),       m = 4(l>>4) + reg
#define RT 4096

#define LDSB(KT) (*(const svec8*)(stp + ((64 * (KT) + 16 * g) ^ swz)))
#define LDSA(J, KT) (*(const svec8*)(ldsA + (((w * 2 + (J)) * 16 + (KT)) << 9) + l * 8))

// full body for kt 0..13 (3 ds_reads: 1 state prefetch d2, 2 A prefetch d1)
#define KTSTEP(KT) do { \
    sbv[((KT) + 2) % 3] = LDSB((KT) + 2); \
    s6[((KT) + 1) & 1] = LDSA(0, (KT) + 1); \
    s7[((KT) + 1) & 1] = LDSA(1, (KT) + 1); \
    svec8 sc = sbv[(KT) % 3]; \
    acc[0] = MFMA16(af[KT][0], sc, acc[0], 0, 0, 0); \
    acc[1] = MFMA16(af[KT][1], sc, acc[1], 0, 0, 0); \
    acc[2] = MFMA16(af[KT][2], sc, acc[2], 0, 0, 0); \
    acc[3] = MFMA16(af[KT][3], sc, acc[3], 0, 0, 0); \
    acc[4] = MFMA16(af[KT][4], sc, acc[4], 0, 0, 0); \
    acc[5] = MFMA16(af[KT][5], sc, acc[5], 0, 0, 0); \
    acc[6] = MFMA16(s6[(KT) & 1], sc, acc[6], 0, 0, 0); \
    acc[7] = MFMA16(s7[(KT) & 1], sc, acc[7], 0, 0, 0); \
    __builtin_amdgcn_sched_group_barrier(0x100, 3, 0); \
    __builtin_amdgcn_sched_group_barrier(0x008, 8, 0); \
} while (0)

// tail bodies (fewer/no prefetches)
#define KTSTEP14() do { \
    s6[1] = LDSA(0, 15); \
    s7[1] = LDSA(1, 15); \
    svec8 sc = sbv[14 % 3]; \
    acc[0] = MFMA16(af[14][0], sc, acc[0], 0, 0, 0); \
    acc[1] = MFMA16(af[14][1], sc, acc[1], 0, 0, 0); \
    acc[2] = MFMA16(af[14][2], sc, acc[2], 0, 0, 0); \
    acc[3] = MFMA16(af[14][3], sc, acc[3], 0, 0, 0); \
    acc[4] = MFMA16(af[14][4], sc, acc[4], 0, 0, 0); \
    acc[5] = MFMA16(af[14][5], sc, acc[5], 0, 0, 0); \
    acc[6] = MFMA16(s6[0], sc, acc[6], 0, 0, 0); \
    acc[7] = MFMA16(s7[0], sc, acc[7], 0, 0, 0); \
    __builtin_amdgcn_sched_group_barrier(0x100, 2, 0); \
    __builtin_amdgcn_sched_group_barrier(0x008, 8, 0); \
} while (0)

#define KTSTEP15() do { \
    svec8 sc = sbv[15 % 3]; \
    acc[0] = MFMA16(af[15][0], sc, acc[0], 0, 0, 0); \
    acc[1] = MFMA16(af[15][1], sc, acc[1], 0, 0, 0); \
    acc[2] = MFMA16(af[15][2], sc, acc[2], 0, 0, 0); \
    acc[3] = MFMA16(af[15][3], sc, acc[3], 0, 0, 0); \
    acc[4] = MFMA16(af[15][4], sc, acc[4], 0, 0, 0); \
    acc[5] = MFMA16(af[15][5], sc, acc[5], 0, 0, 0); \
    acc[6] = MFMA16(s6[1], sc, acc[6], 0, 0, 0); \
    acc[7] = MFMA16(s7[1], sc, acc[7], 0, 0, 0); \
    __builtin_amdgcn_sched_group_barrier(0x008, 8, 0); \
} while (0)

__global__ __launch_bounds__(256, 1)
void recur1cu_kernel(const unsigned short* __restrict__ Abf,   // [512][512] bf16, A[n][k]
                     const unsigned short* __restrict__ bx,    // [65536][512] bf16, row = t*16+b
                     unsigned short* __restrict__ states)      // [65536][512] bf16, row = t*16+b
{
    __shared__ __align__(16) unsigned short st[16 * 512];            // 16 KB state, row=b, XOR-swizzled
    __shared__ __align__(16) unsigned short ldsA[4 * 2 * 16 * 512];  // 128 KB: [w][mt-6][kt][frag 1KB]
    const int tid = threadIdx.x;
    const int w = tid >> 6, l = tid & 63;
    const int g = l >> 4, r16 = l & 15;
    const int nbase = w * 128;
    const int swz = (r16 & 7) << 4;

    // ---- stage A mt=6,7 into LDS, fragment-linear ----
    #pragma unroll
    for (int j = 0; j < 2; ++j)
        #pragma unroll
        for (int kt = 0; kt < 16; ++kt) {
            usvec8 v = *(const usvec8*)(Abf + (size_t)(nbase + 16 * (6 + j) + r16) * 512
                                        + 32 * kt + 8 * g);
            *(usvec8*)(ldsA + (((w * 2 + j) * 16 + kt) << 9) + l * 8) = v;
        }

    // ---- preload A mt=0..5 into registers (96 frags = 384 VGPRs) ----
    svec8 af[16][6];
    #pragma unroll
    for (int kt = 0; kt < 16; ++kt)
        #pragma unroll
        for (int mt = 0; mt < 6; ++mt)
            af[kt][mt] = *(const svec8*)(Abf + (size_t)(nbase + 16 * mt + r16) * 512
                                         + 32 * kt + 8 * g);

    __syncthreads();

    // ---- t = 0: state0 = relu(bx[0]) ----
    {
        const unsigned short* bp = bx + (size_t)r16 * 512 + nbase + 4 * g;
        char* stq = (char*)st + r16 * 1024;
        #pragma unroll
        for (int mt = 0; mt < 8; ++mt) {
            unsigned long long u = *(const unsigned long long*)(bp + 16 * mt);
            usvec4 o;
            #pragma unroll
            for (int r = 0; r < 4; ++r)
                o[r] = f2bf(fmaxf(bf2f((unsigned short)((u >> (16 * r)) & 0xffffu)), 0.0f));
            *(usvec4*)(stq + ((2 * (nbase + 16 * mt + 4 * g)) ^ swz)) = o;
        }
    }
    __syncthreads();

    // export lane mapping: wave w exports state rows 4w..4w+3
    const int erow = 4 * w + (l >> 4);
    const int eswz = (erow & 7) << 4;
    const int ecol = (l & 15) * 16;     // 16B chunk base; +256*jj

    #pragma unroll 1
    for (int t = 1; t < RT; ++t) {
        // A) export state_{t-1} from LDS early (store drain overlaps MFMA region)
        {
            const char* sp = (const char*)st + erow * 1024;
            char* gp = (char*)states + ((size_t)(t - 1) * 16 + erow) * 1024 + ecol;
            #pragma unroll
            for (int jj = 0; jj < 4; ++jj) {
                uivec4 v = *(const uivec4*)(sp + ((ecol + 256 * jj) ^ eswz));
                *(uivec4*)(gp + 256 * jj) = v;
            }
        }

        // B) bx[t] loads (consumed in epilogue; latency hidden by MFMA region)
        unsigned long long bq[8];
        {
            const unsigned short* bp = bx + ((size_t)t * 16 + r16) * 512 + nbase + 4 * g;
            #pragma unroll
            for (int mt = 0; mt < 8; ++mt)
                bq[mt] = *(const unsigned long long*)(bp + 16 * mt);
        }

        // C) MFMA region: software-pipelined ds_reads + sched_group_barrier per kt
        fvec4 acc[8];
        #pragma unroll
        for (int mt = 0; mt < 8; ++mt) acc[mt] = fvec4{0.f, 0.f, 0.f, 0.f};
        const char* stp = (const char*)st + r16 * 1024;
        svec8 sbv[3], s6[2], s7[2];
        sbv[0] = LDSB(0); sbv[1] = LDSB(1);
        s6[0] = LDSA(0, 0); s7[0] = LDSA(1, 0);
        KTSTEP(0);  KTSTEP(1);  KTSTEP(2);  KTSTEP(3);
        KTSTEP(4);  KTSTEP(5);  KTSTEP(6);  KTSTEP(7);
        KTSTEP(8);  KTSTEP(9);  KTSTEP(10); KTSTEP(11);
        KTSTEP(12); KTSTEP(13); KTSTEP14(); KTSTEP15();

        __syncthreads();   // B1: all reads of st done before overwrite

        // D) epilogue: + bx, relu, pack bf16, write st (swizzled)
        {
            char* stq = (char*)st + r16 * 1024;
            #pragma unroll
            for (int mt = 0; mt < 8; ++mt) {
                unsigned long long u = bq[mt];
                usvec4 o;
                #pragma unroll
                for (int r = 0; r < 4; ++r) {
                    float b = bf2f((unsigned short)((u >> (16 * r)) & 0xffffu));
                    o[r] = f2bf(fmaxf(acc[mt][r] + b, 0.0f));
                }
                *(usvec4*)(stq + ((2 * (nbase + 16 * mt + 4 * g)) ^ swz)) = o;
            }
        }
        __syncthreads();   // B2: st(t) complete before next step's reads
    }

    // ---- final export: state_{RT-1} ----
    {
        const char* sp = (const char*)st + erow * 1024;
        char* gp = (char*)states + ((size_t)(RT - 1) * 16 + erow) * 1024 + ecol;
        #pragma unroll
        for (int jj = 0; jj < 4; ++jj) {
            uivec4 v = *(const uivec4*)(sp + ((ecol + 256 * jj) ^ eswz));
            *(uivec4*)(gp + 256 * jj) = v;
        }
    }
}

extern "C" void kernel_launch(void* const* d_in, const int* in_sizes, int n_in,
                              void* d_out, int out_size, void* d_ws, size_t ws_size,
                              hipStream_t stream) {
    const float* x = (const float*)d_in[0];   // [16][4096][512]
    const float* A = (const float*)d_in[1];   // [512][512]
    const float* B = (const float*)d_in[2];   // [512][512]
    const float* C = (const float*)d_in[3];   // [512][512]
    float* out = (float*)d_out;               // [16][4096][512]

    char* ws = (char*)d_ws;
    unsigned short* Abf = (unsigned short*)(ws + 0);                          // 512KB
    unsigned short* Bbf = (unsigned short*)(ws + (size_t)(1 << 19));          // 512KB
    unsigned short* Cbf = (unsigned short*)(ws + (size_t)(2 << 19));          // 512KB
    unsigned short* bx  = (unsigned short*)(ws + (size_t)(4 << 19));          // 64MB: [65536][512] bf16
    unsigned short* states = (unsigned short*)(ws + (size_t)(4 << 19) + ((size_t)1 << 26)); // 64MB

    cvt_kernel<<<64, 256, 0, stream>>>(A, Abf, 512 * 512 / 4);
    cvt_kernel<<<64, 256, 0, stream>>>(B, Bbf, 512 * 512 / 4);
    cvt_kernel<<<64, 256, 0, stream>>>(C, Cbf, 512 * 512 / 4);

    dim3 grid(1024, 8);
    // bx[t*16+b][n] = sum_d x[b][t][d] * B[n][d]
    gemm512<true, false><<<grid, 256, 0, stream>>>((const void*)x, Bbf, (void*)bx);
    // sequential recurrence on one CU, states[t*16+b][n]
    recur1cu_kernel<<<1, 256, 0, stream>>>(Abf, bx, states);
    // y[b][t][j] = sum_n states[t*16+b][n] * C[j][n]
    gemm512<false, true><<<grid, 256, 0, stream>>>((const void*)states, Cbf, (void*)out);
}

// Round 5
// 7275.268 us; speedup vs baseline: 4.5268x; 1.6744x over previous
//
#include <hip/hip_runtime.h>
#include <hip/hip_bf16.h>

typedef __attribute__((ext_vector_type(4))) float  fvec4;
typedef __attribute__((ext_vector_type(8))) short  svec8;    // 8 bf16 (4 VGPRs), MFMA A/B frag
typedef __attribute__((ext_vector_type(8))) unsigned short usvec8;
typedef __attribute__((ext_vector_type(4))) unsigned short usvec4;
typedef __attribute__((ext_vector_type(4))) unsigned int   uivec4;

#define MFMA16 __builtin_amdgcn_mfma_f32_16x16x32_bf16

static __device__ __forceinline__ unsigned short f2bf(float f) {
    __hip_bfloat16 h = __float2bfloat16(f);
    return __builtin_bit_cast(unsigned short, h);
}
static __device__ __forceinline__ float bf2f(unsigned short u) {
    unsigned int v = ((unsigned int)u) << 16;
    return __builtin_bit_cast(float, v);
}

// ---------------- fp32 -> bf16 convert ----------------
__global__ void cvt_kernel(const float* __restrict__ in, unsigned short* __restrict__ out, int n4) {
    int stride = gridDim.x * blockDim.x;
    for (int i = blockIdx.x * blockDim.x + threadIdx.x; i < n4; i += stride) {
        fvec4 v = ((const fvec4*)in)[i];
        usvec4 u;
        u[0] = f2bf(v[0]); u[1] = f2bf(v[1]); u[2] = f2bf(v[2]); u[3] = f2bf(v[3]);
        ((usvec4*)out)[i] = u;
    }
}

// ---------------- GEMM: out[m][n] = sum_k lhs[m][k] * rhs[n][k], K=N=512 ----------------
// (unchanged since round 1 — verified)
template<bool LHS_F32_PERM, bool OUT_PERM>
__global__ __launch_bounds__(256)
void gemm512(const void* __restrict__ lhsv, const unsigned short* __restrict__ rhs,
             void* __restrict__ outv)
{
    __shared__ __align__(16) unsigned short smA[64 * 72];
    __shared__ __align__(16) unsigned short smB[64 * 72];
    const int tid = threadIdx.x;
    const int m0 = blockIdx.x * 64;
    const int n0 = blockIdx.y * 64;
    const int w = tid >> 6, l = tid & 63;
    const int g = l >> 4, r16 = l & 15;
    const int wm = (w >> 1) * 32, wn = (w & 1) * 32;
    const int ri = tid >> 2;
    const int kseg = (tid & 3) * 16;

    fvec4 acc[2][2] = {};

    for (int k0 = 0; k0 < 512; k0 += 64) {
        if (LHS_F32_PERM) {
            const float* x = (const float*)lhsv;
            int m = m0 + ri;
            size_t base = ((size_t)(m & 15) * 4096 + (size_t)(m >> 4)) * 512 + k0 + kseg;
            usvec8 o0, o1;
            fvec4 v0 = *(const fvec4*)(x + base + 0);
            fvec4 v1 = *(const fvec4*)(x + base + 4);
            fvec4 v2 = *(const fvec4*)(x + base + 8);
            fvec4 v3 = *(const fvec4*)(x + base + 12);
            o0[0]=f2bf(v0[0]); o0[1]=f2bf(v0[1]); o0[2]=f2bf(v0[2]); o0[3]=f2bf(v0[3]);
            o0[4]=f2bf(v1[0]); o0[5]=f2bf(v1[1]); o0[6]=f2bf(v1[2]); o0[7]=f2bf(v1[3]);
            o1[0]=f2bf(v2[0]); o1[1]=f2bf(v2[1]); o1[2]=f2bf(v2[2]); o1[3]=f2bf(v2[3]);
            o1[4]=f2bf(v3[0]); o1[5]=f2bf(v3[1]); o1[6]=f2bf(v3[2]); o1[7]=f2bf(v3[3]);
            *(usvec8*)(smA + ri * 72 + kseg)     = o0;
            *(usvec8*)(smA + ri * 72 + kseg + 8) = o1;
        } else {
            const unsigned short* s = (const unsigned short*)lhsv;
            size_t base = (size_t)(m0 + ri) * 512 + k0 + kseg;
            *(usvec8*)(smA + ri * 72 + kseg)     = *(const usvec8*)(s + base);
            *(usvec8*)(smA + ri * 72 + kseg + 8) = *(const usvec8*)(s + base + 8);
        }
        {
            size_t base = (size_t)(n0 + ri) * 512 + k0 + kseg;
            *(usvec8*)(smB + ri * 72 + kseg)     = *(const usvec8*)(rhs + base);
            *(usvec8*)(smB + ri * 72 + kseg + 8) = *(const usvec8*)(rhs + base + 8);
        }
        __syncthreads();
        #pragma unroll
        for (int kt = 0; kt < 2; ++kt) {
            svec8 a0 = *(const svec8*)(smA + (wm +      r16) * 72 + 32 * kt + 8 * g);
            svec8 a1 = *(const svec8*)(smA + (wm + 16 + r16) * 72 + 32 * kt + 8 * g);
            svec8 b0 = *(const svec8*)(smB + (wn +      r16) * 72 + 32 * kt + 8 * g);
            svec8 b1 = *(const svec8*)(smB + (wn + 16 + r16) * 72 + 32 * kt + 8 * g);
            acc[0][0] = MFMA16(a0, b0, acc[0][0], 0, 0, 0);
            acc[0][1] = MFMA16(a0, b1, acc[0][1], 0, 0, 0);
            acc[1][0] = MFMA16(a1, b0, acc[1][0], 0, 0, 0);
            acc[1][1] = MFMA16(a1, b1, acc[1][1], 0, 0, 0);
        }
        __syncthreads();
    }
    #pragma unroll
    for (int mt = 0; mt < 2; ++mt)
    #pragma unroll
    for (int nt = 0; nt < 2; ++nt)
    #pragma unroll
    for (int r = 0; r < 4; ++r) {
        int m = m0 + wm + 16 * mt + 4 * g + r;
        int n = n0 + wn + 16 * nt + r16;
        float v = acc[mt][nt][r];
        if (OUT_PERM) {
            float* out = (float*)outv;
            out[((size_t)(m & 15) * 4096 + (size_t)(m >> 4)) * 512 + n] = v;
        } else {
            unsigned short* out = (unsigned short*)outv;
            out[(size_t)m * 512 + n] = f2bf(v);
        }
    }
}

// ---------------- recurrence: ONE workgroup, 4 waves, A in AGPR+VGPR+LDS ----------------
// Wave w owns n_out in [128w, 128w+128), FULL k.
// A-split per wave (128 frags = 128KB/wave):
//   mt 0..3 x kt 0..15 -> AGPRs via inline-asm "a" constraint (64 frags = 256 AGPRs, full file)
//   mt 4..5 x kt 0..15 -> arch VGPRs (32 frags = 128 VGPRs)
//   mt 6..7 x kt 0..15 -> LDS, fragment-linear (32 frags = 32KB/wave, 128KB total)
// Arch-VGPR demand ~230 <= 256 -> no spill by construction (round 3/4 failure mode).
// All inner MFMAs are inline asm (v_mfma D, A, B, C with D==C accumulate):
//   compiler can't see MFMA hazards through asm, so we add s_nop fences manually.
// Mappings (numerically verified rounds 2-4, absmax 0.03125):
//   A-frag: lane l -> m = l&15 (n_out local), k = 32kt + 8(l>>4) + e
//   B-frag: lane l -> n = l&15 (batch),       k = 32kt + 8(l>>4) + e
//   C/D:    lane l -> n = l&15 (batch),       m = 4(l>>4) + reg
#define RT 4096

#define LDSB(KT) (*(const svec8*)(stp + ((64 * (KT) + 16 * g) ^ swz)))
#define LDSA(J, KT) (*(const svec8*)(ldsA + (((w * 2 + (J)) * 16 + (KT)) << 9) + l * 8))

#define MFA(ACC, AF, SB) asm("v_mfma_f32_16x16x32_bf16 %0, %1, %2, %0" : "+v"(ACC) : "a"(AF), "v"(SB))
#define MFV(ACC, AF, SB) asm("v_mfma_f32_16x16x32_bf16 %0, %1, %2, %0" : "+v"(ACC) : "v"(AF), "v"(SB))

// body for kt 0..13: prefetch all three LDS streams at distance 2, then 8 MFMAs
#define KTSTEP(KT) do { \
    sbv[((KT) + 2) % 3] = LDSB((KT) + 2); \
    s6a[((KT) + 2) % 3] = LDSA(0, (KT) + 2); \
    s7a[((KT) + 2) % 3] = LDSA(1, (KT) + 2); \
    svec8 sc = sbv[(KT) % 3]; \
    MFA(acc[0], af_a[KT][0], sc); \
    MFA(acc[1], af_a[KT][1], sc); \
    MFA(acc[2], af_a[KT][2], sc); \
    MFA(acc[3], af_a[KT][3], sc); \
    MFV(acc[4], af_v[KT][0], sc); \
    MFV(acc[5], af_v[KT][1], sc); \
    MFV(acc[6], s6a[(KT) % 3], sc); \
    MFV(acc[7], s7a[(KT) % 3], sc); \
    __builtin_amdgcn_sched_barrier(0); \
} while (0)

// tail body for kt 14,15: no prefetch
#define KTSTEPNP(KT) do { \
    svec8 sc = sbv[(KT) % 3]; \
    MFA(acc[0], af_a[KT][0], sc); \
    MFA(acc[1], af_a[KT][1], sc); \
    MFA(acc[2], af_a[KT][2], sc); \
    MFA(acc[3], af_a[KT][3], sc); \
    MFV(acc[4], af_v[KT][0], sc); \
    MFV(acc[5], af_v[KT][1], sc); \
    MFV(acc[6], s6a[(KT) % 3], sc); \
    MFV(acc[7], s7a[(KT) % 3], sc); \
    __builtin_amdgcn_sched_barrier(0); \
} while (0)

__global__ __launch_bounds__(256, 1)
void recur1cu_kernel(const unsigned short* __restrict__ Abf,   // [512][512] bf16, A[n][k]
                     const unsigned short* __restrict__ bx,    // [65536][512] bf16, row = t*16+b
                     unsigned short* __restrict__ states)      // [65536][512] bf16, row = t*16+b
{
    __shared__ __align__(16) unsigned short st[16 * 512];            // 16 KB state, row=b, XOR-swizzled
    __shared__ __align__(16) unsigned short ldsA[4 * 2 * 16 * 512];  // 128 KB: [w][mt-6][kt][frag 1KB]
    const int tid = threadIdx.x;
    const int w = tid >> 6, l = tid & 63;
    const int g = l >> 4, r16 = l & 15;
    const int nbase = w * 128;
    const int swz = (r16 & 7) << 4;

    // ---- stage A mt=6,7 into LDS, fragment-linear ----
    #pragma unroll
    for (int j = 0; j < 2; ++j)
        #pragma unroll
        for (int kt = 0; kt < 16; ++kt) {
            usvec8 v = *(const usvec8*)(Abf + (size_t)(nbase + 16 * (6 + j) + r16) * 512
                                        + 32 * kt + 8 * g);
            *(usvec8*)(ldsA + (((w * 2 + j) * 16 + kt) << 9) + l * 8) = v;
        }

    // ---- preload A mt=0..3 (AGPR-destined, used only via "a" asm operands) ----
    svec8 af_a[16][4];
    #pragma unroll
    for (int kt = 0; kt < 16; ++kt)
        #pragma unroll
        for (int mt = 0; mt < 4; ++mt)
            af_a[kt][mt] = *(const svec8*)(Abf + (size_t)(nbase + 16 * mt + r16) * 512
                                           + 32 * kt + 8 * g);

    // ---- preload A mt=4,5 into arch VGPRs (128 regs) ----
    svec8 af_v[16][2];
    #pragma unroll
    for (int kt = 0; kt < 16; ++kt)
        #pragma unroll
        for (int j = 0; j < 2; ++j)
            af_v[kt][j] = *(const svec8*)(Abf + (size_t)(nbase + 16 * (4 + j) + r16) * 512
                                          + 32 * kt + 8 * g);

    __syncthreads();

    // ---- t = 0: state0 = relu(bx[0]) ----
    {
        const unsigned short* bp = bx + (size_t)r16 * 512 + nbase + 4 * g;
        char* stq = (char*)st + r16 * 1024;
        #pragma unroll
        for (int mt = 0; mt < 8; ++mt) {
            unsigned long long u = *(const unsigned long long*)(bp + 16 * mt);
            usvec4 o;
            #pragma unroll
            for (int r = 0; r < 4; ++r)
                o[r] = f2bf(fmaxf(bf2f((unsigned short)((u >> (16 * r)) & 0xffffu)), 0.0f));
            *(usvec4*)(stq + ((2 * (nbase + 16 * mt + 4 * g)) ^ swz)) = o;
        }
    }
    __syncthreads();

    // export lane mapping: wave w exports state rows 4w..4w+3
    const int erow = 4 * w + (l >> 4);
    const int eswz = (erow & 7) << 4;
    const int ecol = (l & 15) * 16;

    #pragma unroll 1
    for (int t = 1; t < RT; ++t) {
        // A) export state_{t-1} early (store drain overlaps MFMA region)
        {
            const char* sp = (const char*)st + erow * 1024;
            char* gp = (char*)states + ((size_t)(t - 1) * 16 + erow) * 1024 + ecol;
            #pragma unroll
            for (int jj = 0; jj < 4; ++jj) {
                uivec4 v = *(const uivec4*)(sp + ((ecol + 256 * jj) ^ eswz));
                *(uivec4*)(gp + 256 * jj) = v;
            }
        }

        // B) bx[t] loads (consumed in epilogue; latency hidden under MFMA region)
        unsigned long long bq[8];
        {
            const unsigned short* bp = bx + ((size_t)t * 16 + r16) * 512 + nbase + 4 * g;
            #pragma unroll
            for (int mt = 0; mt < 8; ++mt)
                bq[mt] = *(const unsigned long long*)(bp + 16 * mt);
        }

        // C) MFMA region
        fvec4 acc[8];
        #pragma unroll
        for (int mt = 0; mt < 8; ++mt) acc[mt] = fvec4{0.f, 0.f, 0.f, 0.f};
        // VALU-write -> MFMA-read-C hazard fence (compiler can't see through asm)
        asm volatile("s_nop 1"
                     : "+v"(acc[0]), "+v"(acc[1]), "+v"(acc[2]), "+v"(acc[3]),
                       "+v"(acc[4]), "+v"(acc[5]), "+v"(acc[6]), "+v"(acc[7]));

        const char* stp = (const char*)st + r16 * 1024;
        svec8 sbv[3], s6a[3], s7a[3];
        sbv[0] = LDSB(0); sbv[1] = LDSB(1);
        s6a[0] = LDSA(0, 0); s6a[1] = LDSA(0, 1);
        s7a[0] = LDSA(1, 0); s7a[1] = LDSA(1, 1);
        KTSTEP(0);  KTSTEP(1);  KTSTEP(2);  KTSTEP(3);
        KTSTEP(4);  KTSTEP(5);  KTSTEP(6);  KTSTEP(7);
        KTSTEP(8);  KTSTEP(9);  KTSTEP(10); KTSTEP(11);
        KTSTEP(12); KTSTEP(13); KTSTEPNP(14); KTSTEPNP(15);

        // MFMA-write -> VALU-read hazard fence
        asm volatile("s_nop 7\n\ts_nop 7"
                     : "+v"(acc[0]), "+v"(acc[1]), "+v"(acc[2]), "+v"(acc[3]),
                       "+v"(acc[4]), "+v"(acc[5]), "+v"(acc[6]), "+v"(acc[7]));

        __syncthreads();   // B1: all reads of st done before overwrite

        // D) epilogue: + bx, relu, pack bf16, write st (swizzled)
        {
            char* stq = (char*)st + r16 * 1024;
            #pragma unroll
            for (int mt = 0; mt < 8; ++mt) {
                unsigned long long u = bq[mt];
                usvec4 o;
                #pragma unroll
                for (int r = 0; r < 4; ++r) {
                    float b = bf2f((unsigned short)((u >> (16 * r)) & 0xffffu));
                    o[r] = f2bf(fmaxf(acc[mt][r] + b, 0.0f));
                }
                *(usvec4*)(stq + ((2 * (nbase + 16 * mt + 4 * g)) ^ swz)) = o;
            }
        }
        __syncthreads();   // B2: st(t) complete before next step's reads
    }

    // ---- final export: state_{RT-1} ----
    {
        const char* sp = (const char*)st + erow * 1024;
        char* gp = (char*)states + ((size_t)(RT - 1) * 16 + erow) * 1024 + ecol;
        #pragma unroll
        for (int jj = 0; jj < 4; ++jj) {
            uivec4 v = *(const uivec4*)(sp + ((ecol + 256 * jj) ^ eswz));
            *(uivec4*)(gp + 256 * jj) = v;
        }
    }
}

extern "C" void kernel_launch(void* const* d_in, const int* in_sizes, int n_in,
                              void* d_out, int out_size, void* d_ws, size_t ws_size,
                              hipStream_t stream) {
    const float* x = (const float*)d_in[0];   // [16][4096][512]
    const float* A = (const float*)d_in[1];   // [512][512]
    const float* B = (const float*)d_in[2];   // [512][512]
    const float* C = (const float*)d_in[3];   // [512][512]
    float* out = (float*)d_out;               // [16][4096][512]

    char* ws = (char*)d_ws;
    unsigned short* Abf = (unsigned short*)(ws + 0);                          // 512KB
    unsigned short* Bbf = (unsigned short*)(ws + (size_t)(1 << 19));          // 512KB
    unsigned short* Cbf = (unsigned short*)(ws + (size_t)(2 << 19));          // 512KB
    unsigned short* bx  = (unsigned short*)(ws + (size_t)(4 << 19));          // 64MB: [65536][512] bf16
    unsigned short* states = (unsigned short*)(ws + (size_t)(4 << 19) + ((size_t)1 << 26)); // 64MB

    cvt_kernel<<<64, 256, 0, stream>>>(A, Abf, 512 * 512 / 4);
    cvt_kernel<<<64, 256, 0, stream>>>(B, Bbf, 512 * 512 / 4);
    cvt_kernel<<<64, 256, 0, stream>>>(C, Cbf, 512 * 512 / 4);

    dim3 grid(1024, 8);
    // bx[t*16+b][n] = sum_d x[b][t][d] * B[n][d]
    gemm512<true, false><<<grid, 256, 0, stream>>>((const void*)x, Bbf, (void*)bx);
    // sequential recurrence on one CU, states[t*16+b][n]
    recur1cu_kernel<<<1, 256, 0, stream>>>(Abf, bx, states);
    // y[b][t][j] = sum_n states[t*16+b][n] * C[j][n]
    gemm512<false, true><<<grid, 256, 0, stream>>>((const void*)states, Cbf, (void*)out);
}